// Round 1
// baseline (363.744 us; speedup 1.0000x reference)
//
#include <hip/hip_runtime.h>
#include <hip/hip_bf16.h>
#include <cstddef>

#define E_TOTAL 30000
#define EB 16

__device__ __constant__ float kCUT_INV = 0.25f;                  // 1/CUTOFF
#define INV_S3 0.57735026918962576f   /* 1/sqrt(3) */
#define PW0    0.10206207261596575f   /* sqrt(1/96) */
#define PW1    0.17677669529663687f   /* sqrt(3/96) */

// ---------------- prep: per-edge hidden vector h[16] -----------------
__global__ void prep_h(const float* __restrict__ dist, const float* __restrict__ freq,
                       const float* __restrict__ w1, const float* __restrict__ b1,
                       float* __restrict__ h_out) {
    int e = blockIdx.x * 256 + threadIdx.x;
    if (e >= E_TOTAL) return;
    float d  = dist[e] * kCUT_INV;
    float d2 = d * d;
    float d5 = d2 * d2 * d;
    float env = 1.0f / d - 28.0f * d5 + 48.0f * d5 * d - 21.0f * d5 * d * d;
    env = (d < 1.0f) ? env : 0.0f;
    float basis[10];
#pragma unroll
    for (int k = 0; k < 10; ++k) basis[k] = env * sinf(freq[k] * d);
#pragma unroll
    for (int j = 0; j < 16; ++j) {
        float a = b1[j];
#pragma unroll
        for (int k = 0; k < 10; ++k) a = fmaf(basis[k], w1[k * 16 + j], a);
        float s = a / (1.0f + __expf(-a));     // silu
        h_out[e * 16 + j] = s;
    }
}

// ---------------- prep: transpose w2 [16][9216] -> w2t [9216][16] ----
__global__ void transpose_w2(const float* __restrict__ w2, float* __restrict__ w2t) {
    int j = blockIdx.y;
    int i = blockIdx.x * 256 + threadIdx.x;
    if (i < 9216) w2t[i * 16 + j] = w2[j * 9216 + i];
}

// ---------------- main fused kernel ----------------------------------
__device__ __forceinline__ float dot16(const float* __restrict__ h,
                                       const float* __restrict__ wr, float bb) {
    float a = fmaf(h[0], wr[0], bb);
    float b = h[1] * wr[1];
    a = fmaf(h[2],  wr[2],  a);  b = fmaf(h[3],  wr[3],  b);
    a = fmaf(h[4],  wr[4],  a);  b = fmaf(h[5],  wr[5],  b);
    a = fmaf(h[6],  wr[6],  a);  b = fmaf(h[7],  wr[7],  b);
    a = fmaf(h[8],  wr[8],  a);  b = fmaf(h[9],  wr[9],  b);
    a = fmaf(h[10], wr[10], a);  b = fmaf(h[11], wr[11], b);
    a = fmaf(h[12], wr[12], a);  b = fmaf(h[13], wr[13], b);
    a = fmaf(h[14], wr[14], a);  b = fmaf(h[15], wr[15], b);
    return a + b;
}

__device__ __forceinline__ void load_wr(const float* __restrict__ w2t, int i, float* wr) {
    const float4* p = reinterpret_cast<const float4*>(w2t + (size_t)i * 16);
    float4 q0 = p[0], q1 = p[1], q2 = p[2], q3 = p[3];
    wr[0]=q0.x; wr[1]=q0.y; wr[2]=q0.z; wr[3]=q0.w;
    wr[4]=q1.x; wr[5]=q1.y; wr[6]=q1.z; wr[7]=q1.w;
    wr[8]=q2.x; wr[9]=q2.y; wr[10]=q2.z; wr[11]=q2.w;
    wr[12]=q3.x; wr[13]=q3.y; wr[14]=q3.z; wr[15]=q3.w;
}

__launch_bounds__(256, 2)
__global__ void conv_main(const float* __restrict__ x, const float* __restrict__ rp,
                          const float* __restrict__ h_arr, const float* __restrict__ w2t,
                          const float* __restrict__ b2, float* __restrict__ out) {
    __shared__ float s_ca[EB][64];     // PW0*sh0*x0
    __shared__ float s_cb[EB][64];     // PW1*INV_S3*x0
    __shared__ float s_cd[EB][32];     // PW0*INV_S3*z
    __shared__ float s_cc[EB][32][3];  // PW1*INV_S3*sh0*x1
    __shared__ float s_x1[EB][32][3];  // raw x1
    __shared__ float s_h [EB][16];
    __shared__ float s_sh[EB][4];

    const int t  = threadIdx.x;
    const int e0 = blockIdx.x * EB;

    // ---- stage per-edge small data ----
    if (t < EB * 4) { int e = t >> 2, c = t & 3; s_sh[e][c] = rp[(e0 + e) * 4 + c]; }
    { int e = t >> 4, c = t & 15; s_h[e][c] = h_arr[(e0 + e) * 16 + c]; }
    __syncthreads();

    for (int idx = t; idx < EB * 160; idx += 256) {
        int e = idx / 160, c = idx - e * 160;
        float v = x[e0 * 160 + idx];
        if (c < 64) {
            s_ca[e][c] = PW0 * s_sh[e][0] * v;
            s_cb[e][c] = (PW1 * INV_S3) * v;
        } else {
            int c2 = c - 64; int u = c2 / 3, m = c2 - u * 3;
            s_x1[e][u][m] = v;
        }
    }
    __syncthreads();

    for (int idx = t; idx < EB * 32; idx += 256) {
        int e = idx >> 5, u = idx & 31;
        float x1a = s_x1[e][u][0], x1b = s_x1[e][u][1], x1c = s_x1[e][u][2];
        float z = x1a * s_sh[e][1] + x1b * s_sh[e][2] + x1c * s_sh[e][3];
        s_cd[e][u] = (PW0 * INV_S3) * z;
        float f = (PW1 * INV_S3) * s_sh[e][0];
        s_cc[e][u][0] = f * x1a; s_cc[e][u][1] = f * x1b; s_cc[e][u][2] = f * x1c;
    }
    __syncthreads();

    const int w     = t & 63;
    const int es    = t >> 6;
    const int ebase = es * 4;          // 4 edges per thread

    float h_reg[4][16];
#pragma unroll
    for (int k = 0; k < 4; ++k)
#pragma unroll
        for (int j = 0; j < 16; ++j) h_reg[k][j] = s_h[ebase + k][j];

    // ================= phase Wa: i = u*64 + w, u in [0,64) ============
    float acc0[4] = {0.f, 0.f, 0.f, 0.f};
#pragma unroll 2
    for (int u = 0; u < 64; ++u) {
        int i = u * 64 + w;
        float wr[16]; load_wr(w2t, i, wr);
        float bb = b2[i];
        float fa[4];
#pragma unroll
        for (int k = 0; k < 4; ++k) fa[k] = s_ca[ebase + k][u];
#pragma unroll
        for (int k = 0; k < 4; ++k) {
            float wt = dot16(h_reg[k], wr, bb);
            acc0[k] = fmaf(wt, fa[k], acc0[k]);
        }
    }

    // ================= phase Wd: i = 7168 + u*64 + w, u in [0,32) =====
#pragma unroll 2
    for (int u = 0; u < 32; ++u) {
        int i = 7168 + u * 64 + w;
        float wr[16]; load_wr(w2t, i, wr);
        float bb = b2[i];
        float fa[4];
#pragma unroll
        for (int k = 0; k < 4; ++k) fa[k] = s_cd[ebase + k][u];
#pragma unroll
        for (int k = 0; k < 4; ++k) {
            float wt = dot16(h_reg[k], wr, bb);
            acc0[k] = fmaf(wt, fa[k], acc0[k]);
        }
    }

    // write out0
#pragma unroll
    for (int k = 0; k < 4; ++k)
        out[(size_t)(e0 + ebase + k) * 160 + w] = acc0[k];

    // ================= phase Wb: 64 lanes fold two u-rows of 32 =======
    const int upar = w >> 5;
    const int wp   = w & 31;
    float acc1b[4] = {0.f, 0.f, 0.f, 0.f};
#pragma unroll 2
    for (int uu = 0; uu < 32; ++uu) {
        int i = 4096 + uu * 64 + w;        // == 4096 + u*32 + wp, u = 2*uu+upar
        int u = 2 * uu + upar;
        float wr[16]; load_wr(w2t, i, wr);
        float bb = b2[i];
        float fa[4];
#pragma unroll
        for (int k = 0; k < 4; ++k) fa[k] = s_cb[ebase + k][u];
#pragma unroll
        for (int k = 0; k < 4; ++k) {
            float wt = dot16(h_reg[k], wr, bb);
            acc1b[k] = fmaf(wt, fa[k], acc1b[k]);
        }
    }

    // ================= phase Wc =======================================
    float acc1c[4][3] = {{0.f,0.f,0.f},{0.f,0.f,0.f},{0.f,0.f,0.f},{0.f,0.f,0.f}};
#pragma unroll 2
    for (int uu = 0; uu < 16; ++uu) {
        int i = 6144 + uu * 64 + w;        // == 6144 + u*32 + wp
        int u = 2 * uu + upar;
        float wr[16]; load_wr(w2t, i, wr);
        float bb = b2[i];
#pragma unroll
        for (int k = 0; k < 4; ++k) {
            float wt = dot16(h_reg[k], wr, bb);
            acc1c[k][0] = fmaf(wt, s_cc[ebase + k][u][0], acc1c[k][0]);
            acc1c[k][1] = fmaf(wt, s_cc[ebase + k][u][1], acc1c[k][1]);
            acc1c[k][2] = fmaf(wt, s_cc[ebase + k][u][2], acc1c[k][2]);
        }
    }

    // ---- reduce the two u-parities (lane w <-> w^32) and write out1 ----
#pragma unroll
    for (int k = 0; k < 4; ++k) {
        float bt = acc1b[k]    + __shfl_xor(acc1b[k],    32, 64);
        float c0 = acc1c[k][0] + __shfl_xor(acc1c[k][0], 32, 64);
        float c1 = acc1c[k][1] + __shfl_xor(acc1c[k][1], 32, 64);
        float c2 = acc1c[k][2] + __shfl_xor(acc1c[k][2], 32, 64);
        if (w < 32) {
            int e = e0 + ebase + k;
            float s1 = s_sh[ebase + k][1], s2 = s_sh[ebase + k][2], s3 = s_sh[ebase + k][3];
            size_t base = (size_t)e * 160 + 64 + wp * 3;
            out[base + 0] = fmaf(bt, s1, c0);
            out[base + 1] = fmaf(bt, s2, c1);
            out[base + 2] = fmaf(bt, s3, c2);
        }
    }
}

extern "C" void kernel_launch(void* const* d_in, const int* in_sizes, int n_in,
                              void* d_out, int out_size, void* d_ws, size_t ws_size,
                              hipStream_t stream) {
    const float* x    = (const float*)d_in[0];
    const float* rp   = (const float*)d_in[1];
    const float* dist = (const float*)d_in[2];
    const float* freq = (const float*)d_in[3];
    const float* w1   = (const float*)d_in[4];
    const float* b1   = (const float*)d_in[5];
    const float* w2   = (const float*)d_in[6];
    const float* b2   = (const float*)d_in[7];
    float* out = (float*)d_out;

    float* h_arr = (float*)d_ws;                 // 30000*16 floats
    float* w2t   = h_arr + (size_t)E_TOTAL * 16; // 9216*16 floats

    prep_h<<<(E_TOTAL + 255) / 256, 256, 0, stream>>>(dist, freq, w1, b1, h_arr);
    transpose_w2<<<dim3(36, 16), 256, 0, stream>>>(w2, w2t);
    conv_main<<<E_TOTAL / EB, 256, 0, stream>>>(x, rp, h_arr, w2t, b2, out);
}

// Round 2
// 134.179 us; speedup vs baseline: 2.7109x; 2.7109x over previous
//
#include <hip/hip_runtime.h>
#include <hip/hip_bf16.h>
#include <cstddef>

#define E_TOTAL 30000
#define INV_S3 0.57735026918962576f   /* 1/sqrt(3) */
#define PW0    0.10206207261596575f   /* sqrt(1/96) */
#define PW1    0.17677669529663687f   /* sqrt(3/96) */

typedef __attribute__((ext_vector_type(8))) short bf16x8;
typedef __attribute__((ext_vector_type(4))) float f32x4;

#define NAB (52*4*64*8)   /* 106496 : B_alpha, K padded 1632->1664 */
#define NBB (34*2*64*8)   /* 34816  : B_beta,  K=1088 */
#define NCB (17*2*64*8)   /* 17408  : B_gamma, K=544  */

__device__ __forceinline__ short f2bf(float v) {
    union { __hip_bfloat16 h; short s; } u;
    u.h = __float2bfloat16(v);
    return u.s;
}

// ---------------- prep: per-edge hidden vector h[16] -----------------
__global__ void prep_h(const float* __restrict__ dist, const float* __restrict__ freq,
                       const float* __restrict__ w1, const float* __restrict__ b1,
                       float* __restrict__ h_out) {
    int e = blockIdx.x * 256 + threadIdx.x;
    if (e >= E_TOTAL) return;
    float d  = dist[e] * 0.25f;
    float d2 = d * d;
    float d5 = d2 * d2 * d;
    float env = 1.0f / d - 28.0f * d5 + 48.0f * d5 * d - 21.0f * d5 * d * d;
    env = (d < 1.0f) ? env : 0.0f;
    float basis[10];
#pragma unroll
    for (int k = 0; k < 10; ++k) basis[k] = env * sinf(freq[k] * d);
#pragma unroll
    for (int j = 0; j < 16; ++j) {
        float a = b1[j];
#pragma unroll
        for (int k = 0; k < 10; ++k) a = fmaf(basis[k], w1[k * 16 + j], a);
        h_out[(size_t)e * 16 + j] = a / (1.0f + __expf(-a));
    }
}

// ------- prep: fragment-ordered, scale-folded bf16 B matrices --------
// layout: Bx[((step32*NT + nt)*64 + lane)*8 + b], lane = kg*16 + jcol,
//         element (kg,b) holds k = step32*32 + kg*8 + b, col w = nt*16 + jcol
__global__ void prep_B(const float* __restrict__ w2, const float* __restrict__ b2,
                       short* __restrict__ Ba, short* __restrict__ Bb, short* __restrict__ Bc) {
    int idx = blockIdx.x * 256 + threadIdx.x;
    if (idx < NAB) {
        int b = idx & 7, lane = (idx >> 3) & 63, nt = (idx >> 9) & 3, ks = idx >> 11;
        int k = ks * 32 + (lane >> 4) * 8 + b, w = nt * 16 + (lane & 15);
        float v;
        if (k < 1024)      { int j = k >> 6, u = k & 63;             v = PW0 * w2[j * 9216 + u * 64 + w]; }
        else if (k < 1536) { int k2 = k - 1024, j = k2 >> 5, u = k2 & 31; v = (PW0 * INV_S3) * w2[j * 9216 + 7168 + u * 64 + w]; }
        else if (k < 1600) { int u = k - 1536;                       v = PW0 * b2[u * 64 + w]; }
        else if (k < 1632) { int u = k - 1600;                       v = (PW0 * INV_S3) * b2[7168 + u * 64 + w]; }
        else v = 0.f;
        Ba[idx] = f2bf(v);
    } else if (idx < NAB + NBB) {
        int i2 = idx - NAB;
        int b = i2 & 7, lane = (i2 >> 3) & 63, nt = (i2 >> 9) & 1, ks = i2 >> 10;
        int k = ks * 32 + (lane >> 4) * 8 + b, w = nt * 16 + (lane & 15);
        float v;
        if (k < 1024) { int j = k >> 6, u = k & 63; v = (PW1 * INV_S3) * w2[j * 9216 + 4096 + u * 32 + w]; }
        else          { int u = k - 1024;           v = (PW1 * INV_S3) * b2[4096 + u * 32 + w]; }
        Bb[i2] = f2bf(v);
    } else if (idx < NAB + NBB + NCB) {
        int i2 = idx - NAB - NBB;
        int b = i2 & 7, lane = (i2 >> 3) & 63, nt = (i2 >> 9) & 1, ks = i2 >> 10;
        int k = ks * 32 + (lane >> 4) * 8 + b, w = nt * 16 + (lane & 15);
        float v;
        if (k < 512) { int j = k >> 5, u = k & 31; v = (PW1 * INV_S3) * w2[j * 9216 + 6144 + u * 32 + w]; }
        else         { int u = k - 512;            v = (PW1 * INV_S3) * b2[6144 + u * 32 + w]; }
        Bc[i2] = f2bf(v);
    }
}

// ---------------- main fused MFMA kernel ----------------------------
// 64 edges/block, 256 threads (4 waves).
// GEMM-a: K=1632(pad 1664), N=64 -> out0 direct
// GEMM-b: K=1088, N=32 -> tb (scaled) into LDS
// GEMM-c: rows (e,m) 192, K=544, N=32 -> tc; epilogue combines with tb*sh1
__launch_bounds__(256, 2)
__global__ void conv_main(const float* __restrict__ x, const float* __restrict__ rp,
                          const float* __restrict__ h_arr, const short* __restrict__ Ba,
                          const short* __restrict__ Bb, const short* __restrict__ Bc,
                          float* __restrict__ out) {
    __shared__ float sx0[64][68];
    __shared__ float sx1[64][100];
    __shared__ float sz [64][36];
    __shared__ float hT [16][64];
    __shared__ float ssh[64][5];
    __shared__ float stbs[64][33];
    __shared__ __align__(16) short sfA[815 * 8];   // padded frag slots: (tile*NKG+kg)*17+row

    const int t    = threadIdx.x;
    const int e0   = blockIdx.x * 64;
    const int lane = t & 63;
    const int wave = t >> 6;
    const int kg   = lane >> 4;      // MFMA k-group
    const int jcol = lane & 15;      // MFMA row/col-in-tile

    // ---------------- staging ----------------
    { int e = t >> 2, c = t & 3;
      ssh[e][c] = (e0 + e < E_TOTAL) ? rp[(size_t)(e0 + e) * 4 + c] : 0.f; }
#pragma unroll
    for (int it = 0; it < 4; ++it) { int idx = it * 256 + t; int e = idx >> 4, j = idx & 15;
      hT[j][e] = (e0 + e < E_TOTAL) ? h_arr[(size_t)(e0 + e) * 16 + j] : 0.f; }
#pragma unroll
    for (int it = 0; it < 40; ++it) { int idx = it * 256 + t; int e = idx / 160, c = idx - e * 160;
      float v = (e0 + e < E_TOTAL) ? x[(size_t)(e0 + e) * 160 + c] : 0.f;
      if (c < 64) sx0[e][c] = v; else sx1[e][c - 64] = v; }
    __syncthreads();
#pragma unroll
    for (int it = 0; it < 8; ++it) { int idx = it * 256 + t; int e = idx >> 5, u = idx & 31;
      sz[e][u] = sx1[e][u*3] * ssh[e][1] + sx1[e][u*3+1] * ssh[e][2] + sx1[e][u*3+2] * ssh[e][3]; }
    __syncthreads();

    // build-thread role for GEMM a/b: edge e = lane, k-subgroup g = wave
    const int e  = lane;
    const int g  = wave;
    const int row = e & 15, et = e >> 4;

    float xreg[16], zreg[8];
#pragma unroll
    for (int b = 0; b < 8; ++b) {
        xreg[b]     = sx0[e][8 * g + b];
        xreg[8 + b] = sx0[e][32 + 8 * g + b];
        zreg[b]     = sz[e][8 * g + b];
    }
    const float sh0 = ssh[e][0];

    const bf16x8* fragp = reinterpret_cast<const bf16x8*>(sfA);
    const bf16x8* Bap = reinterpret_cast<const bf16x8*>(Ba);
    const bf16x8* Bbp = reinterpret_cast<const bf16x8*>(Bb);
    const bf16x8* Bcp = reinterpret_cast<const bf16x8*>(Bc);

    // ================= GEMM-a: 26 chunks of K=64 =====================
    f32x4 accA[4] = {};
    bf16x8 b0 = Bap[(0 * 4 + wave) * 64 + lane];
    bf16x8 b1v = Bap[(1 * 4 + wave) * 64 + lane];
    for (int ks = 0; ks < 26; ++ks) {
        float flo[8], fhi[8];
        if (ks < 16) {
            float c = sh0 * hT[ks][e];
#pragma unroll
            for (int b = 0; b < 8; ++b) { flo[b] = c * xreg[b]; fhi[b] = c * xreg[8 + b]; }
        } else if (ks < 24) {
            float clo = hT[2 * (ks - 16)][e], chi = hT[2 * (ks - 16) + 1][e];
#pragma unroll
            for (int b = 0; b < 8; ++b) { flo[b] = clo * zreg[b]; fhi[b] = chi * zreg[b]; }
        } else if (ks == 24) {
#pragma unroll
            for (int b = 0; b < 8; ++b) { flo[b] = sh0 * xreg[b]; fhi[b] = sh0 * xreg[8 + b]; }
        } else {
#pragma unroll
            for (int b = 0; b < 8; ++b) { flo[b] = zreg[b]; fhi[b] = 0.f; }
        }
        bf16x8 plo, phi;
#pragma unroll
        for (int b = 0; b < 8; ++b) { plo[b] = f2bf(flo[b]); phi[b] = f2bf(fhi[b]); }
        *reinterpret_cast<bf16x8*>(sfA + ((et * 8 + g) * 17 + row) * 8)     = plo;
        *reinterpret_cast<bf16x8*>(sfA + ((et * 8 + g + 4) * 17 + row) * 8) = phi;
        __syncthreads();
        bf16x8 blo = b0, bhi = b1v;
        if (ks + 1 < 26) {
            b0  = Bap[(((ks + 1) * 2) * 4 + wave) * 64 + lane];
            b1v = Bap[(((ks + 1) * 2 + 1) * 4 + wave) * 64 + lane];
        }
#pragma unroll
        for (int mt = 0; mt < 4; ++mt) {
            bf16x8 alo = fragp[(mt * 8 + kg) * 17 + jcol];
            bf16x8 ahi = fragp[(mt * 8 + kg + 4) * 17 + jcol];
            accA[mt] = __builtin_amdgcn_mfma_f32_16x16x32_bf16(alo, blo, accA[mt], 0, 0, 0);
            accA[mt] = __builtin_amdgcn_mfma_f32_16x16x32_bf16(ahi, bhi, accA[mt], 0, 0, 0);
        }
        __syncthreads();
    }
#pragma unroll
    for (int mt = 0; mt < 4; ++mt)
#pragma unroll
        for (int r = 0; r < 4; ++r) {
            int e_ = mt * 16 + 4 * kg + r;
            if (e0 + e_ < E_TOTAL) out[(size_t)(e0 + e_) * 160 + wave * 16 + jcol] = accA[mt][r];
        }

    // ================= GEMM-b: 17 chunks of K=64 =====================
    const int ntB = wave & 1, mtbB = (wave >> 1) * 2;
    f32x4 accB[2] = {};
    b0  = Bbp[(0 * 2 + ntB) * 64 + lane];
    b1v = Bbp[(1 * 2 + ntB) * 64 + lane];
    for (int ks = 0; ks < 17; ++ks) {
        float flo[8], fhi[8];
        if (ks < 16) {
            float c = hT[ks][e];
#pragma unroll
            for (int b = 0; b < 8; ++b) { flo[b] = c * xreg[b]; fhi[b] = c * xreg[8 + b]; }
        } else {
#pragma unroll
            for (int b = 0; b < 8; ++b) { flo[b] = xreg[b]; fhi[b] = xreg[8 + b]; }
        }
        bf16x8 plo, phi;
#pragma unroll
        for (int b = 0; b < 8; ++b) { plo[b] = f2bf(flo[b]); phi[b] = f2bf(fhi[b]); }
        *reinterpret_cast<bf16x8*>(sfA + ((et * 8 + g) * 17 + row) * 8)     = plo;
        *reinterpret_cast<bf16x8*>(sfA + ((et * 8 + g + 4) * 17 + row) * 8) = phi;
        __syncthreads();
        bf16x8 blo = b0, bhi = b1v;
        if (ks + 1 < 17) {
            b0  = Bbp[(((ks + 1) * 2) * 2 + ntB) * 64 + lane];
            b1v = Bbp[(((ks + 1) * 2 + 1) * 2 + ntB) * 64 + lane];
        }
#pragma unroll
        for (int i = 0; i < 2; ++i) {
            int mt = mtbB + i;
            bf16x8 alo = fragp[(mt * 8 + kg) * 17 + jcol];
            bf16x8 ahi = fragp[(mt * 8 + kg + 4) * 17 + jcol];
            accB[i] = __builtin_amdgcn_mfma_f32_16x16x32_bf16(alo, blo, accB[i], 0, 0, 0);
            accB[i] = __builtin_amdgcn_mfma_f32_16x16x32_bf16(ahi, bhi, accB[i], 0, 0, 0);
        }
        __syncthreads();
    }
#pragma unroll
    for (int i = 0; i < 2; ++i)
#pragma unroll
        for (int r = 0; r < 4; ++r) {
            int e_ = (mtbB + i) * 16 + 4 * kg + r;
            stbs[e_][ntB * 16 + jcol] = accB[i][r];
        }

    // ================= GEMM-c: 17 steps of K=32, rows (m*64+e) =======
    const int eg = t >> 2, gg = t & 3;      // build role: 1 edge, 1 k-subgroup, 3 m-rows
    float x1r[24];
#pragma unroll
    for (int i = 0; i < 24; ++i) x1r[i] = sx1[eg][24 * gg + i];
    const float sh0g = ssh[eg][0];
    const int ntC = wave & 1, mtbC = (wave >> 1) * 6;

    f32x4 accC[6] = {};
    b0 = Bcp[(0 * 2 + ntC) * 64 + lane];
    for (int ks = 0; ks < 17; ++ks) {
        float c = (ks < 16) ? sh0g * hT[ks][eg] : sh0g;
#pragma unroll
        for (int m = 0; m < 3; ++m) {
            bf16x8 pk;
#pragma unroll
            for (int b = 0; b < 8; ++b) pk[b] = f2bf(c * x1r[b * 3 + m]);
            int mt = m * 4 + (eg >> 4);
            *reinterpret_cast<bf16x8*>(sfA + ((mt * 4 + gg) * 17 + (eg & 15)) * 8) = pk;
        }
        __syncthreads();
        bf16x8 bcur = b0;
        if (ks + 1 < 17) b0 = Bcp[((ks + 1) * 2 + ntC) * 64 + lane];
#pragma unroll
        for (int i = 0; i < 6; ++i) {
            bf16x8 a = fragp[((mtbC + i) * 4 + kg) * 17 + jcol];
            accC[i] = __builtin_amdgcn_mfma_f32_16x16x32_bf16(a, bcur, accC[i], 0, 0, 0);
        }
        __syncthreads();
    }
#pragma unroll
    for (int i = 0; i < 6; ++i) {
        int mt = mtbC + i, m = mt >> 2, et_ = mt & 3;
#pragma unroll
        for (int r = 0; r < 4; ++r) {
            int el = et_ * 16 + 4 * kg + r;
            float val = stbs[el][ntC * 16 + jcol] * ssh[el][1 + m] + accC[i][r];
            if (e0 + el < E_TOTAL) out[(size_t)(e0 + el) * 160 + 64 + (ntC * 16 + jcol) * 3 + m] = val;
        }
    }
}

extern "C" void kernel_launch(void* const* d_in, const int* in_sizes, int n_in,
                              void* d_out, int out_size, void* d_ws, size_t ws_size,
                              hipStream_t stream) {
    const float* x    = (const float*)d_in[0];
    const float* rp   = (const float*)d_in[1];
    const float* dist = (const float*)d_in[2];
    const float* freq = (const float*)d_in[3];
    const float* w1   = (const float*)d_in[4];
    const float* b1   = (const float*)d_in[5];
    const float* w2   = (const float*)d_in[6];
    const float* b2   = (const float*)d_in[7];
    float* out = (float*)d_out;

    float* h_arr = (float*)d_ws;                          // 30000*16 f32 = 1.92 MB
    short* Ba = (short*)((char*)d_ws + 1920000);          // NAB bf16
    short* Bb = Ba + NAB;
    short* Bc = Bb + NBB;

    prep_h<<<(E_TOTAL + 255) / 256, 256, 0, stream>>>(dist, freq, w1, b1, h_arr);
    prep_B<<<(NAB + NBB + NCB) / 256, 256, 0, stream>>>(w2, b2, Ba, Bb, Bc);
    conv_main<<<(E_TOTAL + 63) / 64, 256, 0, stream>>>(x, rp, h_arr, Ba, Bb, Bc, out);
}

// Round 3
// 110.355 us; speedup vs baseline: 3.2961x; 1.2159x over previous
//
#include <hip/hip_runtime.h>
#include <hip/hip_bf16.h>
#include <cstddef>

#define E_TOTAL 30000
#define INV_S3 0.57735026918962576f
#define PW0    0.10206207261596575f
#define PW1    0.17677669529663687f

typedef __attribute__((ext_vector_type(8))) short bf16x8;
typedef __attribute__((ext_vector_type(4))) float f32x4;

#define NA_SH (34*6*512)   /* 104448 shorts: B-alpha, K=1088 (34 chunks), N=96 */
#define NB_SH (17*4*512)   /* 34816  shorts: B-beta,  K=544,  N=64 */
#define NC_SH (17*2*512)   /* 17408  shorts: B-gamma, K=544,  N=32 */
#define NH_BLKS ((E_TOTAL + 255) / 256)                 /* 118 */
#define NB_BLKS ((NA_SH + NB_SH + NC_SH) / 256)         /* 612 */

__device__ __forceinline__ short f2bf(float v) {
    union { __hip_bfloat16 h; short s; } u;
    u.h = __float2bfloat16(v);
    return u.s;
}
__device__ __forceinline__ f32x4 ld4(const float* p) {
    return *reinterpret_cast<const f32x4*>(p);
}

// ================= prep: h (silu MLP layer 1) + fragment-ordered B ==========
__global__ void prep_all(const float* __restrict__ dist, const float* __restrict__ freq,
                         const float* __restrict__ w1, const float* __restrict__ b1,
                         const float* __restrict__ w2, const float* __restrict__ b2,
                         float* __restrict__ h_out,
                         short* __restrict__ Ba, short* __restrict__ Bb, short* __restrict__ Bc)
{
    const float C1 = PW1 * INV_S3, C2 = PW0 * INV_S3;
    if (blockIdx.x < NH_BLKS) {
        int e = blockIdx.x * 256 + threadIdx.x;
        if (e >= E_TOTAL) return;
        float d  = dist[e] * 0.25f;
        float d2 = d * d, d5 = d2 * d2 * d;
        float env = 1.0f / d - 28.0f * d5 + 48.0f * d5 * d - 21.0f * d5 * d * d;
        env = (d < 1.0f) ? env : 0.0f;
        float basis[10];
#pragma unroll
        for (int k = 0; k < 10; ++k) basis[k] = env * sinf(freq[k] * d);
#pragma unroll
        for (int j = 0; j < 16; ++j) {
            float a = b1[j];
#pragma unroll
            for (int k = 0; k < 10; ++k) a = fmaf(basis[k], w1[k * 16 + j], a);
            h_out[(size_t)e * 16 + j] = a / (1.0f + __expf(-a));
        }
        return;
    }
    int idx = (blockIdx.x - NH_BLKS) * 256 + threadIdx.x;
    // layout for all B: [(chunk*NT + nt)*512 + lane*8 + b]; lane=(kg<<4)|jc;
    // element = B[k = chunk*32 + kg*8 + b][col = nt*16 + jc]
    if (idx < NA_SH) {
        int b = idx & 7, lane = (idx >> 3) & 63, t2 = idx >> 9;
        int nt = t2 % 6, c = t2 / 6;
        int kg = lane >> 4, jc = lane & 15, w = nt * 16 + jc;
        int cc = (c < 17) ? c : c - 17;                 // j (or 16 = bias row)
        int u  = ((c < 17) ? 0 : 32) + kg * 8 + b;      // x0 index
        float v;
        if (w < 64) v = (cc < 16) ? PW0 * w2[cc * 9216 + u * 64 + w]
                                  : PW0 * b2[u * 64 + w];
        else { int wb = w - 64;
               v = (cc < 16) ? C1 * w2[cc * 9216 + 4096 + u * 32 + wb]
                             : C1 * b2[4096 + u * 32 + wb]; }
        Ba[idx] = f2bf(v);
    } else if (idx < NA_SH + NB_SH) {
        int i2 = idx - NA_SH;
        int b = i2 & 7, lane = (i2 >> 3) & 63, t2 = i2 >> 9;
        int nt = t2 & 3, c = t2 >> 2;
        int kg = lane >> 4, jc = lane & 15, w = nt * 16 + jc;
        int u = kg * 8 + b;                              // z index
        float v = (c < 16) ? C2 * w2[c * 9216 + 7168 + u * 64 + w]
                           : C2 * b2[7168 + u * 64 + w];
        Bb[i2] = f2bf(v);
    } else if (idx < NA_SH + NB_SH + NC_SH) {
        int i2 = idx - NA_SH - NB_SH;
        int b = i2 & 7, lane = (i2 >> 3) & 63, t2 = i2 >> 9;
        int nt = t2 & 1, c = t2 >> 1;
        int kg = lane >> 4, jc = lane & 15, w = nt * 16 + jc;
        int u = kg * 8 + b;                              // x1 u-index
        float v = (c < 16) ? C1 * w2[c * 9216 + 6144 + u * 32 + w]
                           : C1 * b2[6144 + u * 32 + w];
        Bc[i2] = f2bf(v);
    }
}

// ================= phase-1: split-K GEMM slice, within-wave LDS transpose ====
// cbuf layout (per-wave 4224B slab): short offset = kg*528 + mt*128 + row*8
// write: lane l -> g*528 + l*8 (contiguous 1KB per g); read: kg*528+mt*128+jc*8
template<int NT>
__device__ __forceinline__ void run_phase1(const float* __restrict__ xa,
        const float* __restrict__ hreg, short* __restrict__ cbuf,
        const short* __restrict__ Bbase, int lane, f32x4 (&acc)[4][6])
{
    const int kg = lane >> 4, jc = lane & 15;
    const bf16x8* Bp = reinterpret_cast<const bf16x8*>(Bbase);
    bf16x8 bpre[NT];
#pragma unroll
    for (int nt = 0; nt < NT; ++nt) bpre[nt] = Bp[nt * 64 + lane];
#pragma unroll 1
    for (int c = 0; c < 17; ++c) {
        bf16x8 bcur[NT];
#pragma unroll
        for (int nt = 0; nt < NT; ++nt) bcur[nt] = bpre[nt];
        if (c < 16) {
#pragma unroll
            for (int nt = 0; nt < NT; ++nt) bpre[nt] = Bp[((c + 1) * NT + nt) * 64 + lane];
        }
        float hc = (c < 16) ? hreg[c] : 1.0f;
#pragma unroll
        for (int g = 0; g < 4; ++g) {
            bf16x8 fr;
#pragma unroll
            for (int b = 0; b < 8; ++b) fr[b] = f2bf(hc * xa[g * 8 + b]);
            *reinterpret_cast<bf16x8*>(cbuf + g * 528 + lane * 8) = fr;
        }
        bf16x8 af[4];   // same-wave DS ops are in-order: no barrier needed
#pragma unroll
        for (int mt = 0; mt < 4; ++mt)
            af[mt] = *reinterpret_cast<const bf16x8*>(cbuf + kg * 528 + mt * 128 + jc * 8);
#pragma unroll
        for (int nt = 0; nt < NT; ++nt)
#pragma unroll
            for (int mt = 0; mt < 4; ++mt)
                acc[mt][nt] = __builtin_amdgcn_mfma_f32_16x16x32_bf16(af[mt], bcur[nt], acc[mt][nt], 0, 0, 0);
    }
}

// ================= gamma: in-lane A build (wave owns edge-tile et) ==========
__device__ __forceinline__ void load_gamma_feats(const float* __restrict__ x,
        const float* __restrict__ h_arr, const float (*ssh)[4], int e0, int et,
        int lane, float* __restrict__ x1s, float* __restrict__ hg, float& sh0g)
{
    const int kg = lane >> 4, jc = lane & 15;
    const int rowA = et * 16 + jc;
    const int eA = e0 + rowA;
    const bool v = eA < E_TOTAL;
    const float* xp = x + (size_t)eA * 160 + 64 + 24 * kg;
#pragma unroll
    for (int i = 0; i < 6; ++i) {
        f32x4 q = v ? ld4(xp + 4 * i) : f32x4{0.f, 0.f, 0.f, 0.f};
        x1s[4*i] = q[0]; x1s[4*i+1] = q[1]; x1s[4*i+2] = q[2]; x1s[4*i+3] = q[3];
    }
    const float* hp = h_arr + (size_t)eA * 16;
#pragma unroll
    for (int i = 0; i < 4; ++i) {
        f32x4 q = v ? ld4(hp + 4 * i) : f32x4{0.f, 0.f, 0.f, 0.f};
        hg[4*i] = q[0]; hg[4*i+1] = q[1]; hg[4*i+2] = q[2]; hg[4*i+3] = q[3];
    }
    sh0g = ssh[rowA][0];
}

__device__ __forceinline__ void run_gamma(const float* __restrict__ x1s,
        const float* __restrict__ hg, float sh0g, const short* __restrict__ Bc,
        int lane, f32x4 (&acc)[3][2])
{
    const bf16x8* Bp = reinterpret_cast<const bf16x8*>(Bc);
    bf16x8 bpre[2];
#pragma unroll
    for (int nt = 0; nt < 2; ++nt) bpre[nt] = Bp[nt * 64 + lane];
#pragma unroll 1
    for (int c = 0; c < 17; ++c) {
        bf16x8 bcur[2]; bcur[0] = bpre[0]; bcur[1] = bpre[1];
        if (c < 16) { bpre[0] = Bp[((c+1)*2    ) * 64 + lane];
                      bpre[1] = Bp[((c+1)*2 + 1) * 64 + lane]; }
        float coef = (c < 16) ? sh0g * hg[c] : sh0g;
        bf16x8 am[3];
#pragma unroll
        for (int m = 0; m < 3; ++m) {
#pragma unroll
            for (int b = 0; b < 8; ++b) am[m][b] = f2bf(coef * x1s[3 * b + m]);
        }
#pragma unroll
        for (int nt = 0; nt < 2; ++nt)
#pragma unroll
            for (int m = 0; m < 3; ++m)
                acc[m][nt] = __builtin_amdgcn_mfma_f32_16x16x32_bf16(am[m], bcur[nt], acc[m][nt], 0, 0, 0);
    }
}

// ================= main fused kernel ========================================
// LDS map: [0,25600) slabA0 (64x100 f32; overlaps 3x4224B phase-1 chunk slabs)
//          [25600,51200) slabA1 ; [51200,68608) slabB (64x68) ; [68608,69632) ssh
__launch_bounds__(256, 2)
__global__ void conv_main(const float* __restrict__ x, const float* __restrict__ rp,
                          const float* __restrict__ h_arr,
                          const short* __restrict__ Ba, const short* __restrict__ Bb,
                          const short* __restrict__ Bc, float* __restrict__ out)
{
    __shared__ __align__(16) char smem[69632];
    float (*slabA0)[100] = reinterpret_cast<float(*)[100]>(smem);
    float (*slabA1)[100] = reinterpret_cast<float(*)[100]>(smem + 25600);
    float (*slabB)[68]   = reinterpret_cast<float(*)[68]>(smem + 51200);
    float (*ssh)[4]      = reinterpret_cast<float(*)[4]>(smem + 68608);

    const int t = threadIdx.x, lane = t & 63, wave = t >> 6;
    const int kg = lane >> 4, jc = lane & 15;
    const int e0 = blockIdx.x * 64;

    { int ee = t >> 2, c4 = t & 3;
      ssh[ee][c4] = (e0 + ee < E_TOTAL) ? rp[(size_t)(e0 + ee) * 4 + c4] : 0.f; }
    __syncthreads();                                     // S1

    f32x4 acc[4][6];
    f32x4 accg[3][2];
    float x1s[24], hg[16], sh0g = 0.f;

    if (wave < 3) {
        // ---- phase 1: split-K slices of alpha (N=96) / beta (N=64) ----
#pragma unroll
        for (int i = 0; i < 4; ++i)
#pragma unroll
            for (int j = 0; j < 6; ++j) acc[i][j] = f32x4{0.f, 0.f, 0.f, 0.f};
        const int e = e0 + lane;
        const bool ev = e < E_TOTAL;
        float hreg[16], xa[32];
        const float* hp = h_arr + (size_t)e * 16;
#pragma unroll
        for (int i = 0; i < 4; ++i) {
            f32x4 q = ev ? ld4(hp + 4 * i) : f32x4{0.f, 0.f, 0.f, 0.f};
            hreg[4*i] = q[0]; hreg[4*i+1] = q[1]; hreg[4*i+2] = q[2]; hreg[4*i+3] = q[3];
        }
        if (wave < 2) {                                  // x0 half
            const float* xp = x + (size_t)e * 160 + wave * 32;
#pragma unroll
            for (int i = 0; i < 8; ++i) {
                f32x4 q = ev ? ld4(xp + 4 * i) : f32x4{0.f, 0.f, 0.f, 0.f};
                xa[4*i] = q[0]; xa[4*i+1] = q[1]; xa[4*i+2] = q[2]; xa[4*i+3] = q[3];
            }
        } else {                                         // z = x1 . sh1
            float s1 = ssh[lane][1], s2 = ssh[lane][2], s3 = ssh[lane][3];
            const float* xp = x + (size_t)e * 160 + 64;
#pragma unroll
            for (int s = 0; s < 4; ++s) {
                float x1t[24];
#pragma unroll
                for (int i = 0; i < 6; ++i) {
                    f32x4 q = ev ? ld4(xp + 24 * s + 4 * i) : f32x4{0.f, 0.f, 0.f, 0.f};
                    x1t[4*i] = q[0]; x1t[4*i+1] = q[1]; x1t[4*i+2] = q[2]; x1t[4*i+3] = q[3];
                }
#pragma unroll
                for (int u = 0; u < 8; ++u)
                    xa[8*s+u] = x1t[3*u] * s1 + x1t[3*u+1] * s2 + x1t[3*u+2] * s3;
            }
        }
        short* cbuf = reinterpret_cast<short*>(smem + wave * 4224);
        if (wave == 0)      run_phase1<6>(xa, hreg, cbuf, Ba,                lane, acc);
        else if (wave == 1) run_phase1<6>(xa, hreg, cbuf, Ba + 17 * 6 * 512, lane, acc);
        else                run_phase1<4>(xa, hreg, cbuf, Bb,                lane, acc);
    } else {
        // ---- wave 3 runs gamma for et=3 during phase 1 ----
#pragma unroll
        for (int i = 0; i < 3; ++i) { accg[i][0] = f32x4{0.f,0.f,0.f,0.f}; accg[i][1] = f32x4{0.f,0.f,0.f,0.f}; }
        load_gamma_feats(x, h_arr, ssh, e0, 3, lane, x1s, hg, sh0g);
        run_gamma(x1s, hg, sh0g, Bc, lane, accg);
    }
    __syncthreads();                                     // S2

    if (wave == 0) {
#pragma unroll
        for (int mt = 0; mt < 4; ++mt)
#pragma unroll
            for (int nt = 0; nt < 6; ++nt)
#pragma unroll
                for (int r = 0; r < 4; ++r)
                    slabA0[mt*16 + 4*kg + r][nt*16 + jc] = acc[mt][nt][r];
    } else if (wave == 1) {
#pragma unroll
        for (int mt = 0; mt < 4; ++mt)
#pragma unroll
            for (int nt = 0; nt < 6; ++nt)
#pragma unroll
                for (int r = 0; r < 4; ++r)
                    slabA1[mt*16 + 4*kg + r][nt*16 + jc] = acc[mt][nt][r];
    } else if (wave == 2) {
#pragma unroll
        for (int mt = 0; mt < 4; ++mt)
#pragma unroll
            for (int nt = 0; nt < 4; ++nt)
#pragma unroll
                for (int r = 0; r < 4; ++r)
                    slabB[mt*16 + 4*kg + r][nt*16 + jc] = acc[mt][nt][r];
    }
    if (wave < 3) load_gamma_feats(x, h_arr, ssh, e0, wave, lane, x1s, hg, sh0g);
    __syncthreads();                                     // S3

    if (wave < 3) {
        // ---- phase 2: gamma for et = wave ----
#pragma unroll
        for (int i = 0; i < 3; ++i) { accg[i][0] = f32x4{0.f,0.f,0.f,0.f}; accg[i][1] = f32x4{0.f,0.f,0.f,0.f}; }
        run_gamma(x1s, hg, sh0g, Bc, lane, accg);
    } else {
        // ---- wave 3: out0 epilogue: sh0*(alpha) + beta ----
        for (int row = 0; row < 64; ++row) {
            if (e0 + row >= E_TOTAL) break;
            float v = ssh[row][0] * (slabA0[row][lane] + slabA1[row][lane]) + slabB[row][lane];
            out[(size_t)(e0 + row) * 160 + lane] = v;
        }
    }

    // ---- gamma epilogue: out1 = tb*sh1[m] + tc (et = wave) ----
    {
        const int et = wave;
#pragma unroll
        for (int m = 0; m < 3; ++m)
#pragma unroll
            for (int nt = 0; nt < 2; ++nt)
#pragma unroll
                for (int r = 0; r < 4; ++r) {
                    int row = et * 16 + 4 * kg + r;
                    int w = nt * 16 + jc;
                    if (e0 + row < E_TOTAL) {
                        float tbv = slabA0[row][64 + w] + slabA1[row][64 + w];
                        out[(size_t)(e0 + row) * 160 + 64 + w * 3 + m] =
                            tbv * ssh[row][1 + m] + accg[m][nt][r];
                    }
                }
    }
}

extern "C" void kernel_launch(void* const* d_in, const int* in_sizes, int n_in,
                              void* d_out, int out_size, void* d_ws, size_t ws_size,
                              hipStream_t stream) {
    const float* x    = (const float*)d_in[0];
    const float* rp   = (const float*)d_in[1];
    const float* dist = (const float*)d_in[2];
    const float* freq = (const float*)d_in[3];
    const float* w1   = (const float*)d_in[4];
    const float* b1   = (const float*)d_in[5];
    const float* w2   = (const float*)d_in[6];
    const float* b2   = (const float*)d_in[7];
    float* out = (float*)d_out;

    float* h_arr = (float*)d_ws;                           // 30000*16*4 = 1.92 MB
    short* Ba = (short*)((char*)d_ws + 1920000);
    short* Bb = Ba + NA_SH;
    short* Bc = Bb + NB_SH;

    prep_all<<<NH_BLKS + NB_BLKS, 256, 0, stream>>>(dist, freq, w1, b1, w2, b2,
                                                    h_arr, Ba, Bb, Bc);
    conv_main<<<(E_TOTAL + 63) / 64, 256, 0, stream>>>(x, rp, h_arr, Ba, Bb, Bc, out);
}